// Round 1
// baseline (147.468 us; speedup 1.0000x reference)
//
#include <hip/hip_runtime.h>

#define BM 64
#define BN 64
#define DD 128
#define PAD_A 132   // floats per row of A tile (row stride: 528B -> 2-way bank alias, free)
#define PAD_B 68    // floats per row of transposed B tile

// ---------------- c_sq kernel ----------------
__global__ void csq_kernel(const float* __restrict__ ctr, float* __restrict__ csq,
                           int C, int Cpad) {
    int c = blockIdx.x * blockDim.x + threadIdx.x;
    if (c >= Cpad) return;
    float s = 0.f;
    if (c < C) {
        const float* p = ctr + (size_t)c * DD;
        #pragma unroll
        for (int k = 0; k < DD / 4; ++k) {
            float4 v = *reinterpret_cast<const float4*>(p + k * 4);
            s = fmaf(v.x, v.x, s); s = fmaf(v.y, v.y, s);
            s = fmaf(v.z, v.z, s); s = fmaf(v.w, v.w, s);
        }
    }
    csq[c] = s;
}

// ---------------- main kernel ----------------
// grid = B/BM blocks, 256 threads. Each block: 64 rows x all C centers.
__global__ __launch_bounds__(256) void center_main(
    const float* __restrict__ emb, const int* __restrict__ tgt,
    const float* __restrict__ ctr, const float* __restrict__ csq,
    float* __restrict__ partials, int B, int C)
{
    __shared__ float sA[BM][PAD_A];     // embeddings tile, row-major
    __shared__ float sB[DD][PAD_B];     // centers tile, TRANSPOSED [dim][col]
    __shared__ float sRT[BM];           // 1 + dis_intra - e_sq per row
    __shared__ int   sTg[BM];           // targets per row
    __shared__ float sRed[4];

    const int t = threadIdx.x;
    const int row0 = blockIdx.x * BM;

    // ---- stage A: 64 rows x 128 floats = 2048 float4, coalesced ----
    #pragma unroll
    for (int i = 0; i < 8; ++i) {
        int f = t + i * 256;         // 0..2047
        int r = f >> 5;              // row
        int cc = f & 31;             // float4 chunk within row
        float4 v = *reinterpret_cast<const float4*>(emb + (size_t)(row0 + r) * DD + cc * 4);
        *reinterpret_cast<float4*>(&sA[r][cc * 4]) = v;
    }
    __syncthreads();

    // ---- per-row term: 1 + ||e - c_y||^2 - ||e||^2 (4 lanes per row) ----
    {
        int r = t >> 2, p = t & 3;
        int y = tgt[row0 + r];
        const float* cy = ctr + (size_t)y * DD;
        float se = 0.f, sd = 0.f;
        #pragma unroll
        for (int k = 0; k < 8; ++k) {
            int d0 = p * 32 + k * 4;
            float4 e = *reinterpret_cast<const float4*>(&sA[r][d0]);
            float4 c = *reinterpret_cast<const float4*>(cy + d0);
            se = fmaf(e.x, e.x, se); se = fmaf(e.y, e.y, se);
            se = fmaf(e.z, e.z, se); se = fmaf(e.w, e.w, se);
            float dx = e.x - c.x, dy = e.y - c.y, dz = e.z - c.z, dw = e.w - c.w;
            sd = fmaf(dx, dx, sd); sd = fmaf(dy, dy, sd);
            sd = fmaf(dz, dz, sd); sd = fmaf(dw, dw, sd);
        }
        se += __shfl_xor(se, 1); se += __shfl_xor(se, 2);
        sd += __shfl_xor(sd, 1); sd += __shfl_xor(sd, 2);
        if (p == 0) { sRT[r] = 1.0f + sd - se; sTg[r] = y; }
    }
    __syncthreads();

    const int tx = t & 15;   // col group (4 cols)
    const int ty = t >> 4;   // row group (4 rows)

    // hoist per-thread row data
    float rt[4]; int tg[4];
    #pragma unroll
    for (int i = 0; i < 4; ++i) { rt[i] = sRT[ty * 4 + i]; tg[i] = sTg[ty * 4 + i]; }

    float thread_sum = 0.f;
    const int nTiles = (C + BN - 1) / BN;

    for (int ct = 0; ct < nTiles; ++ct) {
        const int c0 = ct * BN;
        __syncthreads();   // guard sB overwrite vs previous tile's reads

        // ---- stage B transposed: lane-major over cols -> conflict-free writes ----
        #pragma unroll
        for (int i = 0; i < 8; ++i) {
            int f = t + i * 256;       // 0..2047
            int c = f & 63;            // col within tile
            int d4 = f >> 6;           // float4 chunk of dim, 0..31
            int cg = c0 + c;
            float4 v = make_float4(0.f, 0.f, 0.f, 0.f);
            if (cg < C) v = *reinterpret_cast<const float4*>(ctr + (size_t)cg * DD + d4 * 4);
            sB[d4 * 4 + 0][c] = v.x;
            sB[d4 * 4 + 1][c] = v.y;
            sB[d4 * 4 + 2][c] = v.z;
            sB[d4 * 4 + 3][c] = v.w;
        }
        __syncthreads();

        // ---- 4x4 register-tile micro-kernel over K=128 ----
        float acc[4][4] = {{0.f}};
        #pragma unroll 4
        for (int kk = 0; kk < DD; kk += 4) {
            float4 a0 = *reinterpret_cast<const float4*>(&sA[ty * 4 + 0][kk]);
            float4 a1 = *reinterpret_cast<const float4*>(&sA[ty * 4 + 1][kk]);
            float4 a2 = *reinterpret_cast<const float4*>(&sA[ty * 4 + 2][kk]);
            float4 a3 = *reinterpret_cast<const float4*>(&sA[ty * 4 + 3][kk]);
            float4 b0 = *reinterpret_cast<const float4*>(&sB[kk + 0][tx * 4]);
            float4 b1 = *reinterpret_cast<const float4*>(&sB[kk + 1][tx * 4]);
            float4 b2 = *reinterpret_cast<const float4*>(&sB[kk + 2][tx * 4]);
            float4 b3 = *reinterpret_cast<const float4*>(&sB[kk + 3][tx * 4]);
#define ROW_FMA(i, ai)                                                                   \
    acc[i][0] = fmaf(ai.x, b0.x, fmaf(ai.y, b1.x, fmaf(ai.z, b2.x, fmaf(ai.w, b3.x, acc[i][0])))); \
    acc[i][1] = fmaf(ai.x, b0.y, fmaf(ai.y, b1.y, fmaf(ai.z, b2.y, fmaf(ai.w, b3.y, acc[i][1])))); \
    acc[i][2] = fmaf(ai.x, b0.z, fmaf(ai.y, b1.z, fmaf(ai.z, b2.z, fmaf(ai.w, b3.z, acc[i][2])))); \
    acc[i][3] = fmaf(ai.x, b0.w, fmaf(ai.y, b1.w, fmaf(ai.z, b2.w, fmaf(ai.w, b3.w, acc[i][3]))));
            ROW_FMA(0, a0)
            ROW_FMA(1, a1)
            ROW_FMA(2, a2)
            ROW_FMA(3, a3)
#undef ROW_FMA
        }

        // ---- fused relu-sum epilogue ----
        #pragma unroll
        for (int j = 0; j < 4; ++j) {
            int c = c0 + tx * 4 + j;
            if (c >= C) continue;
            float cs = csq[c];
            #pragma unroll
            for (int i = 0; i < 4; ++i) {
                if (c == tg[i]) continue;
                float arg = rt[i] - cs + 2.0f * acc[i][j];
                thread_sum += fmaxf(arg, 0.f);
            }
        }
    }

    // ---- block reduction (deterministic) ----
    float s = thread_sum;
    #pragma unroll
    for (int off = 32; off; off >>= 1) s += __shfl_down(s, off);
    if ((t & 63) == 0) sRed[t >> 6] = s;
    __syncthreads();
    if (t == 0) partials[blockIdx.x] = sRed[0] + sRed[1] + sRed[2] + sRed[3];
}

// ---------------- final reduction ----------------
__global__ void reduce_kernel(const float* __restrict__ partials, int n,
                              float* __restrict__ out, double invDenom) {
    __shared__ double sRed[4];
    int t = threadIdx.x;  // 256
    double s = 0.0;
    for (int i = t; i < n; i += 256) s += (double)partials[i];
    #pragma unroll
    for (int off = 32; off; off >>= 1) s += __shfl_down(s, off);
    if ((t & 63) == 0) sRed[t >> 6] = s;
    __syncthreads();
    if (t == 0) out[0] = (float)((sRed[0] + sRed[1] + sRed[2] + sRed[3]) * invDenom);
}

extern "C" void kernel_launch(void* const* d_in, const int* in_sizes, int n_in,
                              void* d_out, int out_size, void* d_ws, size_t ws_size,
                              hipStream_t stream) {
    const float* emb = (const float*)d_in[0];
    const int*   tgt = (const int*)d_in[1];
    const float* ctr = (const float*)d_in[2];

    const int B = in_sizes[1];            // 32768
    const int C = in_sizes[2] / DD;       // 1000
    const int Cpad = ((C + BN - 1) / BN) * BN;   // 1024
    const int nblk = B / BM;              // 512

    float* csq      = (float*)d_ws;       // [Cpad]
    float* partials = csq + Cpad;         // [nblk]

    csq_kernel<<<(Cpad + 255) / 256, 256, 0, stream>>>(ctr, csq, C, Cpad);
    center_main<<<nblk, 256, 0, stream>>>(emb, tgt, ctr, csq, partials, B, C);
    reduce_kernel<<<1, 256, 0, stream>>>(partials, nblk, (float*)d_out,
                                         1.0 / ((double)B * (double)(C - 1)));
}

// Round 2
// 27.383 us; speedup vs baseline: 5.3853x; 5.3853x over previous
//
#include <hip/hip_runtime.h>

#define DD 128

typedef __attribute__((ext_vector_type(8))) short short8;
typedef __attribute__((ext_vector_type(4))) float f32x4;

typedef __attribute__((address_space(1))) const void gvoid_t;
typedef __attribute__((address_space(3))) void svoid_t;
#define GLOAD_LDS16(g, s) __builtin_amdgcn_global_load_lds((gvoid_t*)(g), (svoid_t*)(s), 16, 0, 0)

__device__ __forceinline__ unsigned int f2bf(float f) {
    unsigned int x = __builtin_bit_cast(unsigned int, f);
    return (x + 0x7fffu + ((x >> 16) & 1u)) >> 16;   // RNE
}
__device__ __forceinline__ unsigned int pack2(float a, float b) {
    return f2bf(a) | (f2bf(b) << 16);
}

// ---------- prep: centers -> swizzled bf16 tiles in ws + csq_half ----------
// thread = (col, quarter q of 32 dims). Padded cols (>=C): zeros, csq_half=1e30.
__global__ void prep_centers(const float* __restrict__ ctr,
                             unsigned char* __restrict__ wsB,
                             float* __restrict__ csqh, int C, int Cpad) {
    int gid = blockIdx.x * 256 + threadIdx.x;
    int col = gid >> 2, q = gid & 3;
    if (col >= Cpad) return;
    const float* src = ctr + (size_t)col * DD + q * 32;
    float cs = 0.f;
    #pragma unroll
    for (int j = 0; j < 4; ++j) {
        float4 v0 = make_float4(0.f,0.f,0.f,0.f), v1 = v0;
        if (col < C) {
            v0 = *(const float4*)(src + j * 8);
            v1 = *(const float4*)(src + j * 8 + 4);
        }
        cs = fmaf(v0.x,v0.x,cs); cs = fmaf(v0.y,v0.y,cs);
        cs = fmaf(v0.z,v0.z,cs); cs = fmaf(v0.w,v0.w,cs);
        cs = fmaf(v1.x,v1.x,cs); cs = fmaf(v1.y,v1.y,cs);
        cs = fmaf(v1.z,v1.z,cs); cs = fmaf(v1.w,v1.w,cs);
        uint4 w;
        w.x = pack2(v0.x, v0.y); w.y = pack2(v0.z, v0.w);
        w.z = pack2(v1.x, v1.y); w.w = pack2(v1.z, v1.w);
        int r = col & 127;
        unsigned off = (unsigned)(col >> 7) * 32768u + (unsigned)r * 256u +
                       ((((unsigned)q * 4u + j) * 16u) ^ (((unsigned)r & 7u) << 4));
        *(uint4*)(wsB + off) = w;
    }
    cs += __shfl_xor(cs, 1);
    cs += __shfl_xor(cs, 2);
    if (q == 0) csqh[col] = (col < C) ? 0.5f * cs : 1e30f;
}

// ---------- main: 64 rows/block x all cols via MFMA ----------
__global__ __launch_bounds__(256, 2) void center_mfma(
    const float* __restrict__ emb, const int* __restrict__ tgt,
    const float* __restrict__ ctr, const unsigned char* __restrict__ wsB,
    const float* __restrict__ csqh, float* __restrict__ partials,
    int B, int C, int NT)
{
    __shared__ uint4 sA4[1024];    // 64 rows x 256 B (bf16, swizzled)
    __shared__ uint4 sB4[2048];    // 128 rows x 256 B
    __shared__ float sRT[64];
    __shared__ float sRed[4];
    unsigned char* sAb = (unsigned char*)sA4;
    unsigned char* sBb = (unsigned char*)sB4;

    const int t = threadIdx.x;
    const int row0 = blockIdx.x * 64;

    // ---- stage A (fp32 -> bf16 swizzled) + per-row rt_half ----
    {
        const int r = t >> 2, q = t & 3;
        const float* srcE = emb + (size_t)(row0 + r) * DD + q * 32;
        const int y = tgt[row0 + r];
        const float* srcC = ctr + (size_t)y * DD + q * 32;
        float se = 0.f, sd = 0.f;
        #pragma unroll
        for (int j = 0; j < 4; ++j) {
            float4 e0 = *(const float4*)(srcE + j * 8);
            float4 e1 = *(const float4*)(srcE + j * 8 + 4);
            float4 c0 = *(const float4*)(srcC + j * 8);
            float4 c1 = *(const float4*)(srcC + j * 8 + 4);
            se = fmaf(e0.x,e0.x,se); se = fmaf(e0.y,e0.y,se);
            se = fmaf(e0.z,e0.z,se); se = fmaf(e0.w,e0.w,se);
            se = fmaf(e1.x,e1.x,se); se = fmaf(e1.y,e1.y,se);
            se = fmaf(e1.z,e1.z,se); se = fmaf(e1.w,e1.w,se);
            float d;
            d = e0.x-c0.x; sd = fmaf(d,d,sd);  d = e0.y-c0.y; sd = fmaf(d,d,sd);
            d = e0.z-c0.z; sd = fmaf(d,d,sd);  d = e0.w-c0.w; sd = fmaf(d,d,sd);
            d = e1.x-c1.x; sd = fmaf(d,d,sd);  d = e1.y-c1.y; sd = fmaf(d,d,sd);
            d = e1.z-c1.z; sd = fmaf(d,d,sd);  d = e1.w-c1.w; sd = fmaf(d,d,sd);
            uint4 w;
            w.x = pack2(e0.x, e0.y); w.y = pack2(e0.z, e0.w);
            w.z = pack2(e1.x, e1.y); w.w = pack2(e1.z, e1.w);
            unsigned off = (unsigned)r * 256u +
                ((((unsigned)q * 4u + j) * 16u) ^ (((unsigned)r & 7u) << 4));
            *(uint4*)(sAb + off) = w;
        }
        se += __shfl_xor(se, 1); se += __shfl_xor(se, 2);
        sd += __shfl_xor(sd, 1); sd += __shfl_xor(sd, 2);
        if (q == 0) sRT[r] = 0.5f * (1.0f + sd - se);
    }
    __syncthreads();

    const int l  = t & 63;
    const int w  = t >> 6;        // wave id 0..3, owns cols w*32..w*32+31 of each tile
    const int li = l & 15;
    const int lh = l >> 4;        // 0..3
    const unsigned swz = ((unsigned)li & 7u) << 4;

    // hoist A fragments (reused for all col tiles): A[m][k], k = 8*lh + e
    short8 aF[4][4];
    #pragma unroll
    for (int mf = 0; mf < 4; ++mf)
        #pragma unroll
        for (int ks = 0; ks < 4; ++ks)
            aF[mf][ks] = *(const short8*)(sAb + (unsigned)(li + 16*mf) * 256u +
                                          (((unsigned)(16*lh + 64*ks)) ^ swz));
    // hoist rt_half for this lane's 16 output rows
    float rtv[16];
    #pragma unroll
    for (int mf = 0; mf < 4; ++mf)
        #pragma unroll
        for (int rr = 0; rr < 4; ++rr)
            rtv[mf*4+rr] = sRT[16*mf + 4*lh + rr];

    float tsum = 0.f;

    for (int nt = 0; nt < NT; ++nt) {
        __syncthreads();   // protect sB vs previous iteration's reads
        const unsigned char* g = wsB + (size_t)nt * 32768;
        #pragma unroll
        for (int i = 0; i < 8; ++i) {
            unsigned off = (unsigned)(i * 256 + t) * 16u;
            GLOAD_LDS16(g + off, sBb + off);
        }
        float cq0 = csqh[nt*128 + w*32 + li];
        float cq1 = csqh[nt*128 + w*32 + 16 + li];
        __syncthreads();   // drains vmcnt: staging visible

        // C-init: 0.5*(1 + dis_intra - e_sq) - 0.5*c_sq  (padded cols -> -1e30)
        f32x4 acc[4][2];
        #pragma unroll
        for (int mf = 0; mf < 4; ++mf)
            #pragma unroll
            for (int rr = 0; rr < 4; ++rr) {
                acc[mf][0][rr] = rtv[mf*4+rr] - cq0;
                acc[mf][1][rr] = rtv[mf*4+rr] - cq1;
            }

        #pragma unroll
        for (int ks = 0; ks < 4; ++ks) {
            unsigned kof = ((unsigned)(16*lh + 64*ks)) ^ swz;
            short8 b0 = *(const short8*)(sBb + (unsigned)(li + 32*w) * 256u + kof);
            short8 b1 = *(const short8*)(sBb + (unsigned)(li + 16 + 32*w) * 256u + kof);
            #pragma unroll
            for (int mf = 0; mf < 4; ++mf) {
                acc[mf][0] = __builtin_amdgcn_mfma_f32_16x16x32_bf16(aF[mf][ks], b0, acc[mf][0], 0, 0, 0);
                acc[mf][1] = __builtin_amdgcn_mfma_f32_16x16x32_bf16(aF[mf][ks], b1, acc[mf][1], 0, 0, 0);
            }
        }

        // epilogue: sum += 2*relu(acc)
        float s0 = 0.f, s1 = 0.f;
        #pragma unroll
        for (int mf = 0; mf < 4; ++mf)
            #pragma unroll
            for (int rr = 0; rr < 4; ++rr) {
                s0 = fmaf(2.0f, fmaxf(acc[mf][0][rr], 0.f), s0);
                s1 = fmaf(2.0f, fmaxf(acc[mf][1][rr], 0.f), s1);
            }
        tsum += s0 + s1;
    }

    // block reduction
    float s = tsum;
    #pragma unroll
    for (int off = 32; off; off >>= 1) s += __shfl_down(s, off);
    if (l == 0) sRed[w] = s;
    __syncthreads();
    if (t == 0) partials[blockIdx.x] = sRed[0] + sRed[1] + sRed[2] + sRed[3];
}

// ---------- final reduction ----------
__global__ void reduce_k(const float* __restrict__ partials, int n,
                         float* __restrict__ out, double diagSub, double invDenom) {
    __shared__ double sRed[4];
    int t = threadIdx.x;
    double s = 0.0;
    for (int i = t; i < n; i += 256) s += (double)partials[i];
    #pragma unroll
    for (int off = 32; off; off >>= 1) s += __shfl_down(s, off);
    if ((t & 63) == 0) sRed[t >> 6] = s;
    __syncthreads();
    if (t == 0) out[0] = (float)(((sRed[0]+sRed[1]+sRed[2]+sRed[3]) - diagSub) * invDenom);
}

extern "C" void kernel_launch(void* const* d_in, const int* in_sizes, int n_in,
                              void* d_out, int out_size, void* d_ws, size_t ws_size,
                              hipStream_t stream) {
    const float* emb = (const float*)d_in[0];
    const int*   tgt = (const int*)d_in[1];
    const float* ctr = (const float*)d_in[2];

    const int B = in_sizes[1];                 // 32768
    const int C = in_sizes[2] / DD;            // 1000
    const int NT = (C + 127) / 128;            // 8
    const int Cpad = NT * 128;                 // 1024
    const int nblk = B / 64;                   // 512

    unsigned char* wsB = (unsigned char*)d_ws;               // NT*32 KB
    float* csqh     = (float*)(wsB + (size_t)NT * 32768);    // [Cpad]
    float* partials = csqh + Cpad;                           // [nblk]

    prep_centers<<<(Cpad * 4 + 255) / 256, 256, 0, stream>>>(ctr, wsB, csqh, C, Cpad);
    center_mfma<<<nblk, 256, 0, stream>>>(emb, tgt, ctr, wsB, csqh, partials, B, C, NT);
    // diagonal terms included above are ~relu(LAMBD)=1 each; subtract exactly B*1
    reduce_k<<<1, 256, 0, stream>>>(partials, nblk, (float*)d_out,
                                    (double)B * 1.0,
                                    1.0 / ((double)B * (double)(C - 1)));
}